// Round 1
// baseline (3765.134 us; speedup 1.0000x reference)
//
#include <hip/hip_runtime.h>
#include <cstdint>
#include <cstddef>

// nODE: 50 Euler steps of  x <- x*(1+dt*gamma) + dt*tanh(x @ W^T + b)
// Round 6 theory: previous kernel was occupancy-starved (128 arch VGPR + 64
// acc AGPR = 192 unified regs -> 2 waves/SIMD -> ONE 8-wave block/CU ->
// phase-lockstep: MFMA/VALU/LDS/L2 pipes run serially, wall ~ sum of pipes).
// Fix:
//  - 32-row block tile (grid 1024), wave tile 32x64: s 32 + acc 32 regs
//  - __launch_bounds__(512,4): 128-reg cap -> 4 waves/SIMD -> 2 independent
//    blocks/CU (16 waves) that anti-phase and overlap pipes
//  - W relaid frag-sequential [w][kb][t][lane] (16 B/frag): one contiguous
//    1 KB load per fragment, single base pointer + imm offsets (saves the
//    bp[4] VGPRs that made 128 infeasible), identical stream order across
//    blocks for L2/L3 locality
//  - numerics bit-identical to R5 (same sigma row-perm, slice order, Euler)

#define D_DIM 512
#define NSTEPS 50
#define A_STRIDE 520   // elems; row = 1040 B (16B-aligned, same as R5)

typedef __bf16 bf16x8 __attribute__((ext_vector_type(8)));
typedef float f32x4 __attribute__((ext_vector_type(4)));
typedef unsigned short ushort8_t __attribute__((ext_vector_type(8)));

__device__ __forceinline__ unsigned short f_to_bf16_bits(float f) {
    union { float f; unsigned int i; } c;
    c.f = f;
    unsigned int u = c.i;
    unsigned int r = (u + 0x7fffu + ((u >> 16) & 1u)) >> 16;  // RNE
    return (unsigned short)r;
}

// Wl frag layout: f = ((w*16 + kb)*4 + t)*64 + l16*4 + quad, elems [f*8+j] =
//   bf16( W[w*64 + sigma(t*16+l16)][kb*32 + quad*8 + j] ),
//   sigma(i) = 4*(i&15) + (i>>4)   (same output-col permutation as R5)
__global__ __launch_bounds__(256) void build_wl(
    const float* __restrict__ W, unsigned short* __restrict__ Wl) {
    int f = blockIdx.x * 256 + threadIdx.x;    // 0..32767, one 8-elem frag each
    int quad = f & 3;
    int l16  = (f >> 2) & 15;
    int t    = (f >> 6) & 3;
    int kb   = (f >> 8) & 15;
    int w    = f >> 12;
    int i    = t * 16 + l16;
    int srow = w * 64 + 4 * (i & 15) + (i >> 4);
    int k0   = kb * 32 + quad * 8;
    float4 a = *(const float4*)&W[(size_t)srow * D_DIM + k0];
    float4 b = *(const float4*)&W[(size_t)srow * D_DIM + k0 + 4];
    ushort8_t o;
    o[0] = f_to_bf16_bits(a.x); o[1] = f_to_bf16_bits(a.y);
    o[2] = f_to_bf16_bits(a.z); o[3] = f_to_bf16_bits(a.w);
    o[4] = f_to_bf16_bits(b.x); o[5] = f_to_bf16_bits(b.y);
    o[6] = f_to_bf16_bits(b.z); o[7] = f_to_bf16_bits(b.w);
    *(ushort8_t*)&Wl[(size_t)f * 8] = o;
}

__global__ __launch_bounds__(512, 4) void node_persist(
    const float* __restrict__ X,              // fp32 [32768][512]
    const unsigned short* __restrict__ Wl,    // bf16 frag-sequential W
    const float* __restrict__ bias,           // [512]
    const float* __restrict__ gamma,          // [512]
    float* __restrict__ Fout)                 // fp32 [32768][512]
{
    __shared__ unsigned short ldsA[32 * A_STRIDE];   // 33,280 B state-hi

    const int tid  = threadIdx.x;
    const int lane = tid & 63;
    const int w    = tid >> 6;        // wave 0..7 -> col strip [w*64, w*64+64)
    const int l16  = lane & 15;
    const int quad = lane >> 4;
    const int bm   = blockIdx.x;      // 0..1023, rows [bm*32, bm*32+32)
    const float dt = 1.0f / 50.0f;

    // Lane's 4 TRUE output cols (thanks to sigma row-perm of W).
    const int ctrue0 = w * 64 + 4 * l16;

    // Single B base pointer; slice kb at +kb*2048 elems, frag t at +t*512.
    const unsigned short* bpw =
        Wl + (size_t)w * 32768 + (size_t)(l16 * 4 + quad) * 8;

    // Column constants.
    float bc_[4], g1_[4];
    {
        float4 b4 = *(const float4*)&bias[ctrue0];
        float4 g4 = *(const float4*)&gamma[ctrue0];
        bc_[0] = b4.x; bc_[1] = b4.y; bc_[2] = b4.z; bc_[3] = b4.w;
        g1_[0] = 1.0f + dt * g4.x; g1_[1] = 1.0f + dt * g4.y;
        g1_[2] = 1.0f + dt * g4.z; g1_[3] = 1.0f + dt * g4.w;
    }

    // Initial state: s[tm][tn][r] = state of (row, ctrue0+tn), tm in {0,1}.
    const int r0 = quad * 4;
    float s[2][4][4];
#pragma unroll
    for (int tm = 0; tm < 2; ++tm)
#pragma unroll
        for (int r = 0; r < 4; ++r) {
            float4 v = *(const float4*)
                &X[(size_t)(bm * 32 + r0 + tm * 16 + r) * D_DIM + ctrue0];
            s[tm][0][r] = v.x; s[tm][1][r] = v.y;
            s[tm][2][r] = v.z; s[tm][3][r] = v.w;
        }

    // Initial state-hi into ldsA.
#pragma unroll
    for (int tm = 0; tm < 2; ++tm)
#pragma unroll
        for (int r = 0; r < 4; ++r) {
            ushort4 h;
            h.x = f_to_bf16_bits(s[tm][0][r]);
            h.y = f_to_bf16_bits(s[tm][1][r]);
            h.z = f_to_bf16_bits(s[tm][2][r]);
            h.w = f_to_bf16_bits(s[tm][3][r]);
            *(ushort4*)&ldsA[(r0 + tm * 16 + r) * A_STRIDE + ctrue0] = h;
        }

    // Prime B register double-buffer with slice 0.
    bf16x8 bf0[4], bf1[4];
#pragma unroll
    for (int t = 0; t < 4; ++t)
        bf0[t] = *reinterpret_cast<const bf16x8*>(bpw + t * 512);

    __syncthreads();   // ldsA fully written

    for (int step = 0; step < NSTEPS; ++step) {
        f32x4 acc[2][4];
#pragma unroll
        for (int tm = 0; tm < 2; ++tm)
#pragma unroll
            for (int tn = 0; tn < 4; ++tn) {
                f32x4 b4 = {bc_[tn], bc_[tn], bc_[tn], bc_[tn]};
                acc[tm][tn] = b4;   // bias folded into acc init
            }

#pragma unroll
        for (int kb2 = 0; kb2 < 8; ++kb2) {
            const int kb = kb2 * 2;
            // Prefetch slice kb+1 into bf1 (L2-hot, contiguous 1 KB/frag).
            {
                const unsigned short* bk = bpw + (kb + 1) * 2048;
#pragma unroll
                for (int t = 0; t < 4; ++t)
                    bf1[t] = *reinterpret_cast<const bf16x8*>(bk + t * 512);
            }
            {
                bf16x8 af[2];
#pragma unroll
                for (int tm = 0; tm < 2; ++tm)
                    af[tm] = *reinterpret_cast<const bf16x8*>(
                        &ldsA[(tm * 16 + l16) * A_STRIDE + kb * 32 + quad * 8]);
#pragma unroll
                for (int tm = 0; tm < 2; ++tm)
#pragma unroll
                    for (int tn = 0; tn < 4; ++tn)
                        acc[tm][tn] = __builtin_amdgcn_mfma_f32_16x16x32_bf16(
                            af[tm], bf0[tn], acc[tm][tn], 0, 0, 0);
            }
            // Prefetch slice kb+2 (wraps to 0 -> ready for next step).
            {
                const unsigned short* bk = bpw + ((kb + 2) & 15) * 2048;
#pragma unroll
                for (int t = 0; t < 4; ++t)
                    bf0[t] = *reinterpret_cast<const bf16x8*>(bk + t * 512);
            }
            {
                bf16x8 af[2];
#pragma unroll
                for (int tm = 0; tm < 2; ++tm)
                    af[tm] = *reinterpret_cast<const bf16x8*>(
                        &ldsA[(tm * 16 + l16) * A_STRIDE + (kb + 1) * 32 + quad * 8]);
#pragma unroll
                for (int tm = 0; tm < 2; ++tm)
#pragma unroll
                    for (int tn = 0; tn < 4; ++tn)
                        acc[tm][tn] = __builtin_amdgcn_mfma_f32_16x16x32_bf16(
                            af[tm], bf1[tn], acc[tm][tn], 0, 0, 0);
            }
        }

        // Euler update in registers (same formulation as R5 -> same numerics).
#pragma unroll
        for (int tm = 0; tm < 2; ++tm)
#pragma unroll
            for (int tn = 0; tn < 4; ++tn)
#pragma unroll
                for (int r = 0; r < 4; ++r) {
                    float y = acc[tm][tn][r];             // includes bias
                    float e = __expf(2.0f * y);
                    float th = 1.0f - 2.0f * __builtin_amdgcn_rcpf(e + 1.0f);
                    s[tm][tn][r] = s[tm][tn][r] * g1_[tn] + dt * th;
                }

        if (step == NSTEPS - 1) break;

        __syncthreads();   // all waves done reading ldsA
#pragma unroll
        for (int tm = 0; tm < 2; ++tm)
#pragma unroll
            for (int r = 0; r < 4; ++r) {
                ushort4 h;
                h.x = f_to_bf16_bits(s[tm][0][r]);
                h.y = f_to_bf16_bits(s[tm][1][r]);
                h.z = f_to_bf16_bits(s[tm][2][r]);
                h.w = f_to_bf16_bits(s[tm][3][r]);
                *(ushort4*)&ldsA[(r0 + tm * 16 + r) * A_STRIDE + ctrue0] = h;
            }
        __syncthreads();   // new state-hi visible
    }

    // Final fp32 store (float4, fully coalesced).
#pragma unroll
    for (int tm = 0; tm < 2; ++tm)
#pragma unroll
        for (int r = 0; r < 4; ++r) {
            float4 v;
            v.x = s[tm][0][r]; v.y = s[tm][1][r];
            v.z = s[tm][2][r]; v.w = s[tm][3][r];
            *(float4*)&Fout[(size_t)(bm * 32 + r0 + tm * 16 + r) * D_DIM + ctrue0] = v;
        }
}

extern "C" void kernel_launch(void* const* d_in, const int* in_sizes, int n_in,
                              void* d_out, int out_size, void* d_ws, size_t ws_size,
                              hipStream_t stream) {
    const float* x  = (const float*)d_in[0];   // [32768][512]
    const float* W  = (const float*)d_in[1];   // [512][512]
    const float* bi = (const float*)d_in[2];   // [512]
    const float* ga = (const float*)d_in[3];   // [512]

    unsigned short* Wl = (unsigned short*)d_ws;   // 512 KB frag-sequential bf16 W

    build_wl<<<128, 256, 0, stream>>>(W, Wl);
    node_persist<<<dim3(1024), dim3(512), 0, stream>>>(
        x, Wl, bi, ga, (float*)d_out);
}

// Round 2
// 1630.852 us; speedup vs baseline: 2.3087x; 2.3087x over previous
//
#include <hip/hip_runtime.h>
#include <cstdint>
#include <cstddef>

// nODE: 50 Euler steps of  x <- x*(1+dt*gamma) + dt*tanh(x @ W^T + b)
// Round 7: revert to R5 shape (64 rows/block, grid 512, 1 block/CU) after R6
// showed B-traffic-per-MFMA is the binding currency, not occupancy.
// New vs R5:
//  - R5 sat at 192/256 unified regs (2 waves/SIMD band): 64 regs were FREE.
//    Spend them persisting 4 of 16 B k-slices in registers (bfp[4][4],
//    64 VGPR), loaded once before the step loop: -25% B L2/HBM traffic and
//    -25% B latency exposure, every step.
//  - Persistent-slice MFMA bursts interleaved between streamed prefetches
//    (j<4 iterations) -> effective prefetch distance ~2x for half the
//    streamed loads.
//  - Keep R6's frag-sequential Wl layout: one contiguous 1 KB load per wave
//    fragment, single base pointer + immediate offsets.
//  - ldsA double-buffered (2 x 66,560 B = 133 KB): ONE barrier per step
//    instead of two (write next state to other buffer, no read-drain wait).
//  - Numerics: same sigma row-perm, same per-slice accumulate (order of
//    k-slices permuted: P12..P15 interleaved -- fp32 acc, tolerance-safe),
//    same Euler formulation.

#define D_DIM 512
#define NSTEPS 50
#define A_STRIDE 520   // elems; row = 1040 B (16B-aligned)

typedef __bf16 bf16x8 __attribute__((ext_vector_type(8)));
typedef float f32x4 __attribute__((ext_vector_type(4)));
typedef unsigned short ushort8_t __attribute__((ext_vector_type(8)));

__device__ __forceinline__ unsigned short f_to_bf16_bits(float f) {
    union { float f; unsigned int i; } c;
    c.f = f;
    unsigned int u = c.i;
    unsigned int r = (u + 0x7fffu + ((u >> 16) & 1u)) >> 16;  // RNE
    return (unsigned short)r;
}

// Wl frag layout: f = ((w*16 + kb)*4 + t)*64 + l16*4 + quad, elems [f*8+j] =
//   bf16( W[w*64 + sigma(t*16+l16)][kb*32 + quad*8 + j] ),
//   sigma(i) = 4*(i&15) + (i>>4)   (same output-col permutation as R5)
__global__ __launch_bounds__(256) void build_wl(
    const float* __restrict__ W, unsigned short* __restrict__ Wl) {
    int f = blockIdx.x * 256 + threadIdx.x;    // 0..32767, one 8-elem frag each
    int quad = f & 3;
    int l16  = (f >> 2) & 15;
    int t    = (f >> 6) & 3;
    int kb   = (f >> 8) & 15;
    int w    = f >> 12;
    int i    = t * 16 + l16;
    int srow = w * 64 + 4 * (i & 15) + (i >> 4);
    int k0   = kb * 32 + quad * 8;
    float4 a = *(const float4*)&W[(size_t)srow * D_DIM + k0];
    float4 b = *(const float4*)&W[(size_t)srow * D_DIM + k0 + 4];
    ushort8_t o;
    o[0] = f_to_bf16_bits(a.x); o[1] = f_to_bf16_bits(a.y);
    o[2] = f_to_bf16_bits(a.z); o[3] = f_to_bf16_bits(a.w);
    o[4] = f_to_bf16_bits(b.x); o[5] = f_to_bf16_bits(b.y);
    o[6] = f_to_bf16_bits(b.z); o[7] = f_to_bf16_bits(b.w);
    *(ushort8_t*)&Wl[(size_t)f * 8] = o;
}

__global__ __launch_bounds__(512, 2) void node_persist(
    const float* __restrict__ X,              // fp32 [32768][512]
    const unsigned short* __restrict__ Wl,    // bf16 frag-sequential W
    const float* __restrict__ bias,           // [512]
    const float* __restrict__ gamma,          // [512]
    float* __restrict__ Fout)                 // fp32 [32768][512]
{
    __shared__ unsigned short ldsA[2][64 * A_STRIDE];   // 2 x 66,560 B

    const int tid  = threadIdx.x;
    const int lane = tid & 63;
    const int w    = tid >> 6;        // wave 0..7 -> col strip [w*64, w*64+64)
    const int l16  = lane & 15;
    const int quad = lane >> 4;
    const int bm   = blockIdx.x;      // 0..511, rows [bm*64, bm*64+64)
    const float dt = 1.0f / 50.0f;

    // Lane's 4 TRUE output cols (thanks to sigma row-perm of W).
    const int ctrue0 = w * 64 + 4 * l16;

    // Single B base pointer; slice kb at +kb*2048 elems, frag t at +t*512.
    const unsigned short* bpw =
        Wl + (size_t)w * 32768 + (size_t)(l16 * 4 + quad) * 8;

    // Column constants.
    float bc_[4], g1_[4];
    {
        float4 b4 = *(const float4*)&bias[ctrue0];
        float4 g4 = *(const float4*)&gamma[ctrue0];
        bc_[0] = b4.x; bc_[1] = b4.y; bc_[2] = b4.z; bc_[3] = b4.w;
        g1_[0] = 1.0f + dt * g4.x; g1_[1] = 1.0f + dt * g4.y;
        g1_[2] = 1.0f + dt * g4.z; g1_[3] = 1.0f + dt * g4.w;
    }

    // Initial state: s[tm][tn][r] = state of (row r0+tm*16+r, col ctrue0+tn).
    const int r0 = quad * 4;
    float s[4][4][4];
#pragma unroll
    for (int tm = 0; tm < 4; ++tm)
#pragma unroll
        for (int r = 0; r < 4; ++r) {
            float4 v = *(const float4*)
                &X[(size_t)(bm * 64 + r0 + tm * 16 + r) * D_DIM + ctrue0];
            s[tm][0][r] = v.x; s[tm][1][r] = v.y;
            s[tm][2][r] = v.z; s[tm][3][r] = v.w;
        }

    // Initial state-hi into ldsA[0].
#pragma unroll
    for (int tm = 0; tm < 4; ++tm)
#pragma unroll
        for (int r = 0; r < 4; ++r) {
            ushort4 h;
            h.x = f_to_bf16_bits(s[tm][0][r]);
            h.y = f_to_bf16_bits(s[tm][1][r]);
            h.z = f_to_bf16_bits(s[tm][2][r]);
            h.w = f_to_bf16_bits(s[tm][3][r]);
            *(ushort4*)&ldsA[0][(r0 + tm * 16 + r) * A_STRIDE + ctrue0] = h;
        }

    // Persistent B slices 12..15 (64 VGPR, loaded ONCE for all 50 steps).
    bf16x8 bfp[4][4];
#pragma unroll
    for (int pj = 0; pj < 4; ++pj)
#pragma unroll
        for (int t = 0; t < 4; ++t)
            bfp[pj][t] = *reinterpret_cast<const bf16x8*>(
                bpw + (12 + pj) * 2048 + t * 512);

    // Prime streamed double-buffer with slice 0.
    bf16x8 bf0[4], bf1[4];
#pragma unroll
    for (int t = 0; t < 4; ++t)
        bf0[t] = *reinterpret_cast<const bf16x8*>(bpw + t * 512);

    __syncthreads();   // ldsA[0] fully written

#define LDB(bf, kb) do {                                                   \
    _Pragma("unroll")                                                      \
    for (int t_ = 0; t_ < 4; ++t_)                                         \
        bf[t_] = *reinterpret_cast<const bf16x8*>(                         \
            bpw + (kb) * 2048 + t_ * 512);                                 \
} while (0)

#define LDA(af, buf, kb) do {                                              \
    _Pragma("unroll")                                                      \
    for (int tm_ = 0; tm_ < 4; ++tm_)                                      \
        af[tm_] = *reinterpret_cast<const bf16x8*>(                        \
            &ldsA[buf][(tm_ * 16 + l16) * A_STRIDE + (kb) * 32 + quad * 8]); \
} while (0)

#define MFMA16(af, bf) do {                                                \
    _Pragma("unroll")                                                      \
    for (int tm_ = 0; tm_ < 4; ++tm_)                                      \
        _Pragma("unroll")                                                  \
        for (int tn_ = 0; tn_ < 4; ++tn_)                                  \
            acc[tm_][tn_] = __builtin_amdgcn_mfma_f32_16x16x32_bf16(       \
                af[tm_], bf[tn_], acc[tm_][tn_], 0, 0, 0);                 \
} while (0)

    int p = 0;
    for (int step = 0; step < NSTEPS; ++step) {
        f32x4 acc[4][4];
#pragma unroll
        for (int tm = 0; tm < 4; ++tm)
#pragma unroll
            for (int tn = 0; tn < 4; ++tn) {
                f32x4 b4 = {bc_[tn], bc_[tn], bc_[tn], bc_[tn]};
                acc[tm][tn] = b4;   // bias folded into acc init
            }

        // Streamed slices 0..11 (double-buffered), persistent slices 12..15
        // interleaved at j<4 to widen prefetch distance.
        bf16x8 af[4];
#pragma unroll
        for (int j = 0; j < 6; ++j) {
            const int kb = 2 * j;
            LDB(bf1, kb + 1);                 // prefetch streamed slice kb+1
            LDA(af, p, kb);
            MFMA16(af, bf0);                  // compute streamed slice kb
            if (j < 4) {                      // persistent slice 12+j: free
                LDA(af, p, 12 + j);           // MFMA burst while bf1 in flight
                MFMA16(af, bfp[j]);
            }
            LDB(bf0, (kb + 2) % 12);          // j=5 wraps to slice 0 (next step)
            LDA(af, p, kb + 1);
            MFMA16(af, bf1);                  // compute streamed slice kb+1
        }

        // Euler update in registers (same formulation -> same numerics).
#pragma unroll
        for (int tm = 0; tm < 4; ++tm)
#pragma unroll
            for (int tn = 0; tn < 4; ++tn)
#pragma unroll
                for (int r = 0; r < 4; ++r) {
                    float y = acc[tm][tn][r];             // includes bias
                    float e = __expf(2.0f * y);
                    float th = 1.0f - 2.0f * __builtin_amdgcn_rcpf(e + 1.0f);
                    s[tm][tn][r] = s[tm][tn][r] * g1_[tn] + dt * th;
                }

        if (step == NSTEPS - 1) break;

        // Write next state-hi to the OTHER buffer; one barrier per step.
#pragma unroll
        for (int tm = 0; tm < 4; ++tm)
#pragma unroll
            for (int r = 0; r < 4; ++r) {
                ushort4 h;
                h.x = f_to_bf16_bits(s[tm][0][r]);
                h.y = f_to_bf16_bits(s[tm][1][r]);
                h.z = f_to_bf16_bits(s[tm][2][r]);
                h.w = f_to_bf16_bits(s[tm][3][r]);
                *(ushort4*)&ldsA[p ^ 1][(r0 + tm * 16 + r) * A_STRIDE + ctrue0] = h;
            }
        __syncthreads();   // new buffer fully written (old reads all done too)
        p ^= 1;
    }

    // Final fp32 store (float4, fully coalesced).
#pragma unroll
    for (int tm = 0; tm < 4; ++tm)
#pragma unroll
        for (int r = 0; r < 4; ++r) {
            float4 v;
            v.x = s[tm][0][r]; v.y = s[tm][1][r];
            v.z = s[tm][2][r]; v.w = s[tm][3][r];
            *(float4*)&Fout[(size_t)(bm * 64 + r0 + tm * 16 + r) * D_DIM + ctrue0] = v;
        }
}

extern "C" void kernel_launch(void* const* d_in, const int* in_sizes, int n_in,
                              void* d_out, int out_size, void* d_ws, size_t ws_size,
                              hipStream_t stream) {
    const float* x  = (const float*)d_in[0];   // [32768][512]
    const float* W  = (const float*)d_in[1];   // [512][512]
    const float* bi = (const float*)d_in[2];   // [512]
    const float* ga = (const float*)d_in[3];   // [512]

    unsigned short* Wl = (unsigned short*)d_ws;   // 512 KB frag-sequential bf16 W

    build_wl<<<128, 256, 0, stream>>>(W, Wl);
    node_persist<<<dim3(512), dim3(512), 0, stream>>>(
        x, Wl, bi, ga, (float*)d_out);
}